// Round 6
// baseline (431.120 us; speedup 1.0000x reference)
//
#include <hip/hip_runtime.h>
#include <math.h>

#define Tt 250
#define TnN 243
#define Nn 256
#define EPS_ 1e-5f

typedef unsigned short u16;
typedef __bf16 bf16x8 __attribute__((ext_vector_type(8)));
typedef float f32x4 __attribute__((ext_vector_type(4)));

__device__ __forceinline__ u16 f2bf(float f) {
    unsigned u = __builtin_bit_cast(unsigned, f);
    u += 0x7FFFu + ((u >> 16) & 1u);
    return (u16)(u >> 16);
}
__device__ __forceinline__ float bf2f(u16 s) {
    unsigned u = ((unsigned)s) << 16;
    return __builtin_bit_cast(float, u);
}

// ---------------- stats: per-batch sum & sumsq ----------------
__global__ void k_stats(const float* __restrict__ x, float* __restrict__ stats) {
    int b = blockIdx.y;
    const float* xb = x + (size_t)b * 64 * 128 * Tt;
    const int n = 64 * 128 * Tt;
    float s = 0.f, s2 = 0.f;
    for (int i = blockIdx.x * blockDim.x + threadIdx.x; i < n; i += gridDim.x * blockDim.x) {
        float v = xb[i];
        s += v; s2 += v * v;
    }
    for (int off = 32; off; off >>= 1) {
        s  += __shfl_down(s, off);
        s2 += __shfl_down(s2, off);
    }
    __shared__ float ls[8], ls2[8];
    int lane = threadIdx.x & 63, w = threadIdx.x >> 6;
    if (lane == 0) { ls[w] = s; ls2[w] = s2; }
    __syncthreads();
    if (threadIdx.x == 0) {
        float a = 0.f, a2 = 0.f;
        int nw = blockDim.x >> 6;
        for (int i = 0; i < nw; i++) { a += ls[i]; a2 += ls2[i]; }
        atomicAdd(&stats[b * 2 + 0], a);
        atomicAdd(&stats[b * 2 + 1], a2);
    }
}

// ---------------- normalize + write xu[n][c][t] (t padded to 256) ----------------
__global__ void k_norm(const float* __restrict__ x, const float* __restrict__ stats,
                       const float* __restrict__ gamma, const float* __restrict__ beta,
                       float* __restrict__ xu) {
    int idx = blockIdx.x * blockDim.x + threadIdx.x;
    const int total = Nn * 64 * Tt;
    if (idx >= total) return;
    int t = idx % Tt;
    int c = (idx / Tt) & 63;
    int n = idx / (Tt * 64);
    int b = n >> 7, f = n & 127;
    const float inv = 1.0f / (float)(64 * 128 * Tt);
    float mean = stats[b * 2 + 0] * inv;
    float var  = stats[b * 2 + 1] * inv - mean * mean;
    float rstd = rsqrtf(var + EPS_);
    float v = x[(((size_t)(b * 64 + c)) * 128 + f) * Tt + t];
    xu[((size_t)(n * 64 + c) << 8) + t] = (v - mean) * rstd * gamma[c] + beta[c];
}

// ---------------- pack all weights to bf16 (transposed to [out][k] layouts) ----------------
__global__ void k_packw(const float* __restrict__ W0, const float* __restrict__ Wr,
                        const float* __restrict__ wct,
                        u16* __restrict__ W0t, u16* __restrict__ Wrt, u16* __restrict__ Wcto) {
    int idx = blockIdx.x * blockDim.x + threadIdx.x;
    if (idx < 131072) {
        int j = idx >> 9, p = idx & 511;
        W0t[idx] = f2bf(W0[(size_t)(j >> 7) * 65536 + p * 128 + (j & 127)]);
    } else if (idx < 180224) {
        int r = idx - 131072;
        int i = r & 63, j = (r >> 6) & 255, lidx = r >> 14;
        Wrt[r] = f2bf(Wr[(size_t)(lidx * 2 + (j >> 7)) * 8192 + i * 128 + (j & 127)]);
    } else if (idx < 212992) {
        int r = idx - 180224;
        int o = r >> 9; int k = r & 511; int kk = k >> 6, ci = k & 63;
        Wcto[r] = f2bf(wct[(size_t)ci * 512 + o * 8 + kk]);
    }
}

// ---------------- im2col (chunk-major): A2[ck][t*256+n][32] , ck = (c*8+kk)/32 ----------------
__global__ __launch_bounds__(256) void k_im2col(const float* __restrict__ xu, u16* __restrict__ A2) {
    __shared__ u16 lx[8][64][40];
    int t0 = blockIdx.x * 32;
    int n0 = blockIdx.y * 8;
    int tid = threadIdx.x;
    #pragma unroll
    for (int it = 0; it < 20; ++it) {
        int task = tid + it * 256;
        int v = task % 10;
        int c = (task / 10) & 63;
        int nn = task / 640;
        float4 f4 = *(const float4*)&xu[((size_t)((n0 + nn) * 64 + c) << 8) + t0 + v * 4];
        lx[nn][c][v * 4 + 0] = f2bf(f4.x);
        lx[nn][c][v * 4 + 1] = f2bf(f4.y);
        lx[nn][c][v * 4 + 2] = f2bf(f4.z);
        lx[nn][c][v * 4 + 3] = f2bf(f4.w);
    }
    __syncthreads();
    for (int it = 0; it < 64; ++it) {
        int task = it * 256 + tid;
        int c = task & 63, nn = (task >> 6) & 7, tt = task >> 9;
        int t = t0 + tt;
        if (t >= TnN) break;
        u16 tmp[8];
        #pragma unroll
        for (int j = 0; j < 8; ++j) tmp[j] = lx[nn][c][tt + j];
        uint4 o;
        o.x = (unsigned)tmp[0] | ((unsigned)tmp[1] << 16);
        o.y = (unsigned)tmp[2] | ((unsigned)tmp[3] << 16);
        o.z = (unsigned)tmp[4] | ((unsigned)tmp[5] << 16);
        o.w = (unsigned)tmp[6] | ((unsigned)tmp[7] << 16);
        // chunk-major: ck = c>>2, within-chunk offset = (c&3)*8
        size_t m = (size_t)t * 256 + n0 + nn;
        *(uint4*)&A2[((size_t)(c >> 2) * 62208 + m) * 32 + (c & 3) * 8] = o;
    }
}

// ---------------- fused layer 0: streamed K=512 GEMM + scan, one block per (n, d) ----------------
// LDS union: phase1 As(256x40)+Bs(128x40) = 30720 B; phase2 U(243x132) = 64152 B
__global__ __launch_bounds__(256) void k_layer0(const u16* __restrict__ A2,
                                                const u16* __restrict__ W0t,  // [256 j][512 k]
                                                const float* __restrict__ v,
                                                const float* __restrict__ bbias,
                                                u16* __restrict__ hout) {
    __shared__ u16 sh[32768];   // 64 KiB
    u16* As = sh;               // 256 x 40
    u16* Bs = sh + 256 * 40;    // 128 x 40
    const int tid = threadIdx.x;
    const int n = blockIdx.x >> 1, d = blockIdx.x & 1;
    const int lane = tid & 63, w = tid >> 6;
    const int ml = lane & 15, q = lane >> 4;
    f32x4 acc[4][8] = {};
    for (int ck = 0; ck < 16; ++ck) {
        #pragma unroll
        for (int i = 0; i < 4; ++i) {
            int task = i * 256 + tid;          // 1024: row(256) x grp(4)
            int row = task >> 2, grp = task & 3;
            uint4 val = make_uint4(0, 0, 0, 0);
            if (row < TnN)
                val = *(const uint4*)&A2[((size_t)ck * 62208 + (size_t)row * 256 + n) * 32 + grp * 8];
            *(uint4*)&As[row * 40 + grp * 8] = val;
        }
        #pragma unroll
        for (int i = 0; i < 2; ++i) {
            int task = i * 256 + tid;          // 512: row(128) x grp(4)
            int row = task >> 2, grp = task & 3;
            *(uint4*)&Bs[row * 40 + grp * 8] =
                *(const uint4*)&W0t[(size_t)(d * 128 + row) * 512 + ck * 32 + grp * 8];
        }
        __syncthreads();
        bf16x8 af[4];
        #pragma unroll
        for (int mt = 0; mt < 4; ++mt)
            af[mt] = *(const bf16x8*)&As[(w * 64 + mt * 16 + ml) * 40 + q * 8];
        #pragma unroll
        for (int nt = 0; nt < 8; ++nt) {
            bf16x8 bfr = *(const bf16x8*)&Bs[(nt * 16 + ml) * 40 + q * 8];
            #pragma unroll
            for (int mt = 0; mt < 4; ++mt)
                acc[mt][nt] = __builtin_amdgcn_mfma_f32_16x16x32_bf16(af[mt], bfr, acc[mt][nt], 0, 0, 0);
        }
        __syncthreads();
    }
    // park U in LDS
    u16* Ul = sh;               // 243 x 132
    #pragma unroll
    for (int mt = 0; mt < 4; ++mt)
        #pragma unroll
        for (int r = 0; r < 4; ++r) {
            int t = w * 64 + mt * 16 + q * 4 + r;
            if (t < TnN) {
                #pragma unroll
                for (int nt = 0; nt < 8; ++nt)
                    Ul[t * 132 + nt * 16 + ml] = f2bf(acc[mt][nt][r]);
            }
        }
    __syncthreads();
    if (tid >= 32) return;
    const int h = tid;
    const float* vv = v + (size_t)d * 64;          // layer 0
    const float* bv = bbias + (size_t)d * 64;
    const float vf = vv[h], vr = vv[32 + h], bf_ = bv[h], br_ = bv[32 + h];
    const int t0 = d ? (TnN - 1) : 0;
    const int dt = d ? -1 : 1;
    float c = 0.f;
    for (int g0 = 0; g0 < TnN; g0 += 8) {
        float gz[8], gf[8], gr_[8], gx[8];
        #pragma unroll
        for (int u = 0; u < 8; ++u) {
            int g = g0 + u; int gg = g < TnN ? g : (TnN - 1);
            int t = t0 + dt * gg;
            const u16* row = &Ul[t * 132];
            gz[u] = bf2f(row[h]); gf[u] = bf2f(row[32 + h]);
            gr_[u] = bf2f(row[64 + h]); gx[u] = bf2f(row[96 + h]);
        }
        #pragma unroll
        for (int u = 0; u < 8; ++u) {
            int g = g0 + u;
            if (g < TnN) {
                float fg = 1.f / (1.f + __expf(-(gf[u] + vf * c + bf_)));
                float rg = 1.f / (1.f + __expf(-(gr_[u] + vr * c + br_)));
                c = fg * c + (1.f - fg) * gz[u];
                float hv = rg * c + (1.f - rg) * gx[u];
                int t = t0 + dt * g;
                hout[(size_t)t * 16384 + (size_t)n * 64 + d * 32 + h] = f2bf(hv);
            }
        }
    }
}

// ---------------- fused layer (1..3): GEMM (K=64) + scan, one block per (n, d) ----------------
__global__ __launch_bounds__(256) void k_layer(const u16* __restrict__ hin,
                                               const u16* __restrict__ Wrt_l, // [256 j][64 i]
                                               const float* __restrict__ v,
                                               const float* __restrict__ bbias,
                                               u16* __restrict__ hout, int layer) {
    __shared__ u16 sh[32768];   // 64 KiB
    u16* Ah = sh;               // 256 rows x 72
    u16* Bs = sh + 256 * 72;    // 128 rows x 72
    const int tid = threadIdx.x;
    const int n = blockIdx.x, d = blockIdx.y;
    #pragma unroll
    for (int it = 0; it < 8; ++it) {
        int task = it * 256 + tid;
        int row = task >> 3, grp = task & 7;
        if (row < TnN)
            *(uint4*)&Ah[row * 72 + grp * 8] = *(const uint4*)&hin[((size_t)row * 256 + n) * 64 + grp * 8];
        else if (row < 256)
            *(uint4*)&Ah[row * 72 + grp * 8] = make_uint4(0, 0, 0, 0);
    }
    #pragma unroll
    for (int it = 0; it < 4; ++it) {
        int task = it * 256 + tid;
        int j = task >> 3, grp = task & 7;
        *(uint4*)&Bs[j * 72 + grp * 8] = *(const uint4*)&Wrt_l[((size_t)(d * 128 + j)) * 64 + grp * 8];
    }
    __syncthreads();
    const int lane = tid & 63, w = tid >> 6;
    const int ml = lane & 15, q = lane >> 4;
    f32x4 acc[4][8] = {};
    #pragma unroll
    for (int c2 = 0; c2 < 2; ++c2) {
        int c0 = c2 * 32;
        bf16x8 af[4];
        #pragma unroll
        for (int mt = 0; mt < 4; ++mt)
            af[mt] = *(const bf16x8*)&Ah[(w * 64 + mt * 16 + ml) * 72 + c0 + q * 8];
        #pragma unroll
        for (int nt = 0; nt < 8; ++nt) {
            bf16x8 bfr = *(const bf16x8*)&Bs[(nt * 16 + ml) * 72 + c0 + q * 8];
            #pragma unroll
            for (int mt = 0; mt < 4; ++mt)
                acc[mt][nt] = __builtin_amdgcn_mfma_f32_16x16x32_bf16(af[mt], bfr, acc[mt][nt], 0, 0, 0);
        }
    }
    __syncthreads();
    u16* Ul = sh;               // 243 rows x 132
    #pragma unroll
    for (int mt = 0; mt < 4; ++mt)
        #pragma unroll
        for (int r = 0; r < 4; ++r) {
            int t = w * 64 + mt * 16 + q * 4 + r;
            if (t < TnN) {
                #pragma unroll
                for (int nt = 0; nt < 8; ++nt)
                    Ul[t * 132 + nt * 16 + ml] = f2bf(acc[mt][nt][r]);
            }
        }
    __syncthreads();
    if (tid >= 32) return;
    const int h = tid;
    const float* vv = v + (size_t)(layer * 2 + d) * 64;
    const float* bv = bbias + (size_t)(layer * 2 + d) * 64;
    const float vf = vv[h], vr = vv[32 + h], bf_ = bv[h], br_ = bv[32 + h];
    const int t0 = d ? (TnN - 1) : 0;
    const int dt = d ? -1 : 1;
    float c = 0.f;
    for (int g0 = 0; g0 < TnN; g0 += 8) {
        float gz[8], gf[8], gr_[8], gx[8];
        #pragma unroll
        for (int u = 0; u < 8; ++u) {
            int g = g0 + u; int gg = g < TnN ? g : (TnN - 1);
            int t = t0 + dt * gg;
            const u16* row = &Ul[t * 132];
            gz[u] = bf2f(row[h]); gf[u] = bf2f(row[32 + h]);
            gr_[u] = bf2f(row[64 + h]); gx[u] = bf2f(row[96 + h]);
        }
        #pragma unroll
        for (int u = 0; u < 8; ++u) {
            int g = g0 + u;
            if (g < TnN) {
                float fg = 1.f / (1.f + __expf(-(gf[u] + vf * c + bf_)));
                float rg = 1.f / (1.f + __expf(-(gr_[u] + vr * c + br_)));
                c = fg * c + (1.f - fg) * gz[u];
                float hv = rg * c + (1.f - rg) * gx[u];
                int t = t0 + dt * g;
                hout[(size_t)t * 16384 + (size_t)n * 64 + d * 32 + h] = f2bf(hv);
            }
        }
    }
}

// ---------------- final conv per-n block: MFMA + bias + residual ----------------
__global__ __launch_bounds__(256) void k_convm(const u16* __restrict__ hL,
                                               const u16* __restrict__ Wc,   // [64 o][512 k]
                                               const float* __restrict__ bct,
                                               const float* __restrict__ x,
                                               float* __restrict__ out) {
    __shared__ u16 As[264 * 72];   // rows: tau+7 for tau in [-7..256]; guards zeroed
    __shared__ u16 Bs[64 * 40];
    const int tid = threadIdx.x;
    const int n = blockIdx.x;
    const int b = n >> 7, f = n & 127;
    #pragma unroll
    for (int it = 0; it < 8; ++it) {
        int task = it * 256 + tid;
        int row = task >> 3, grp = task & 7;
        if (row < TnN)
            *(uint4*)&As[(row + 7) * 72 + grp * 8] = *(const uint4*)&hL[((size_t)row * 256 + n) * 64 + grp * 8];
    }
    if (tid < 168) {               // zero guards: rows 0..6 and 250..263
        int r = tid >> 3, grp = tid & 7;
        int row = r < 7 ? r : (TnN + r);
        *(uint4*)&As[row * 72 + grp * 8] = make_uint4(0, 0, 0, 0);
    }
    const int lane = tid & 63, w = tid >> 6;
    const int ml = lane & 15, q = lane >> 4;
    f32x4 acc[4][4] = {};
    for (int kc = 0; kc < 16; ++kc) {
        int kk = kc >> 1, ci0 = (kc & 1) * 32;
        {
            int o = tid >> 2, grp = tid & 3;   // all 256 threads, full 32 columns
            *(uint4*)&Bs[o * 40 + grp * 8] = *(const uint4*)&Wc[(size_t)o * 512 + kc * 32 + grp * 8];
        }
        __syncthreads();
        bf16x8 af[4], bfv[4];
        #pragma unroll
        for (int mt = 0; mt < 4; ++mt)
            af[mt] = *(const bf16x8*)&As[(w * 64 + mt * 16 + ml - kk + 7) * 72 + ci0 + q * 8];
        #pragma unroll
        for (int nt = 0; nt < 4; ++nt)
            bfv[nt] = *(const bf16x8*)&Bs[(nt * 16 + ml) * 40 + q * 8];
        #pragma unroll
        for (int mt = 0; mt < 4; ++mt)
            #pragma unroll
            for (int nt = 0; nt < 4; ++nt)
                acc[mt][nt] = __builtin_amdgcn_mfma_f32_16x16x32_bf16(af[mt], bfv[nt], acc[mt][nt], 0, 0, 0);
        __syncthreads();
    }
    float bc[4];
    #pragma unroll
    for (int nt = 0; nt < 4; ++nt) bc[nt] = bct[nt * 16 + ml];
    #pragma unroll
    for (int mt = 0; mt < 4; ++mt)
        #pragma unroll
        for (int r = 0; r < 4; ++r) {
            int t = w * 64 + mt * 16 + q * 4 + r;
            if (t < Tt) {
                #pragma unroll
                for (int nt = 0; nt < 4; ++nt) {
                    int o = nt * 16 + ml;
                    size_t idx = ((size_t)(b * 64 + o) * 128 + f) * Tt + t;
                    out[idx] = acc[mt][nt][r] + bc[nt] + x[idx];
                }
            }
        }
}

extern "C" void kernel_launch(void* const* d_in, const int* in_sizes, int n_in,
                              void* d_out, int out_size, void* d_ws, size_t ws_size,
                              hipStream_t stream) {
    (void)in_sizes; (void)n_in; (void)out_size; (void)ws_size;
    const float* x     = (const float*)d_in[0];
    const float* gamma = (const float*)d_in[1];
    const float* beta  = (const float*)d_in[2];
    const float* W0    = (const float*)d_in[3];
    const float* Wr    = (const float*)d_in[4];
    const float* v     = (const float*)d_in[5];
    const float* bb    = (const float*)d_in[6];
    const float* wct   = (const float*)d_in[7];
    const float* bct   = (const float*)d_in[8];
    float* out = (float*)d_out;

    char* base = (char*)d_ws;
    float* stats = (float*)base;
    u16* W0t  = (u16*)(base + 256);                      // 262144 B
    u16* Wrt  = (u16*)(base + 256 + 262144);             // 98304 B
    u16* Wcto = (u16*)(base + 256 + 262144 + 98304);     // 65536 B
    char* base2 = base + 426240;
    float* xu = (float*)base2;                           // 16,777,216 B (dead after im2col)
    u16* h0   = (u16*)base2;                             // alias: 7,962,624 B
    u16* h1   = (u16*)(base2 + 8 * 1024 * 1024);         // 7,962,624 B
    char* base3 = base2 + 31850496;
    u16* A2   = (u16*)base3;                             // 63,700,992 B (live through k_layer0)

    hipMemsetAsync(stats, 0, 32, stream);
    k_stats<<<dim3(128, 2), 256, 0, stream>>>(x, stats);
    k_norm<<<(Nn * 64 * Tt + 255) / 256, 256, 0, stream>>>(x, stats, gamma, beta, xu);
    k_packw<<<(212992 + 255) / 256, 256, 0, stream>>>(W0, Wr, wct, W0t, Wrt, Wcto);
    k_im2col<<<dim3(8, 32), 256, 0, stream>>>(xu, A2);

    k_layer0<<<dim3(512), 256, 0, stream>>>(A2, W0t, v, bb, h0);

    k_layer<<<dim3(256, 2), 256, 0, stream>>>(h0, Wrt,         v, bb, h1, 1);
    k_layer<<<dim3(256, 2), 256, 0, stream>>>(h1, Wrt + 16384, v, bb, h0, 2);
    k_layer<<<dim3(256, 2), 256, 0, stream>>>(h0, Wrt + 32768, v, bb, h1, 3);

    k_convm<<<dim3(256), 256, 0, stream>>>(h1, Wcto, bct, x, out);
}

// Round 7
// 380.853 us; speedup vs baseline: 1.1320x; 1.1320x over previous
//
#include <hip/hip_runtime.h>
#include <math.h>

#define Tt 250
#define TnN 243
#define Nn 256
#define EPS_ 1e-5f

typedef unsigned short u16;
typedef __bf16 bf16x8 __attribute__((ext_vector_type(8)));
typedef float f32x4 __attribute__((ext_vector_type(4)));

__device__ __forceinline__ u16 f2bf(float f) {
    unsigned u = __builtin_bit_cast(unsigned, f);
    u += 0x7FFFu + ((u >> 16) & 1u);
    return (u16)(u >> 16);
}
__device__ __forceinline__ float bf2f(u16 s) {
    unsigned u = ((unsigned)s) << 16;
    return __builtin_bit_cast(float, u);
}

// ---------------- stats: per-batch sum & sumsq ----------------
__global__ void k_stats(const float* __restrict__ x, float* __restrict__ stats) {
    int b = blockIdx.y;
    const float* xb = x + (size_t)b * 64 * 128 * Tt;
    const int n = 64 * 128 * Tt;
    float s = 0.f, s2 = 0.f;
    for (int i = blockIdx.x * blockDim.x + threadIdx.x; i < n; i += gridDim.x * blockDim.x) {
        float v = xb[i];
        s += v; s2 += v * v;
    }
    for (int off = 32; off; off >>= 1) {
        s  += __shfl_down(s, off);
        s2 += __shfl_down(s2, off);
    }
    __shared__ float ls[8], ls2[8];
    int lane = threadIdx.x & 63, w = threadIdx.x >> 6;
    if (lane == 0) { ls[w] = s; ls2[w] = s2; }
    __syncthreads();
    if (threadIdx.x == 0) {
        float a = 0.f, a2 = 0.f;
        int nw = blockDim.x >> 6;
        for (int i = 0; i < nw; i++) { a += ls[i]; a2 += ls2[i]; }
        atomicAdd(&stats[b * 2 + 0], a);
        atomicAdd(&stats[b * 2 + 1], a2);
    }
}

// ---------------- normalize + write xu[n][c][t] (t padded to 256) ----------------
__global__ void k_norm(const float* __restrict__ x, const float* __restrict__ stats,
                       const float* __restrict__ gamma, const float* __restrict__ beta,
                       float* __restrict__ xu) {
    int idx = blockIdx.x * blockDim.x + threadIdx.x;
    const int total = Nn * 64 * Tt;
    if (idx >= total) return;
    int t = idx % Tt;
    int c = (idx / Tt) & 63;
    int n = idx / (Tt * 64);
    int b = n >> 7, f = n & 127;
    const float inv = 1.0f / (float)(64 * 128 * Tt);
    float mean = stats[b * 2 + 0] * inv;
    float var  = stats[b * 2 + 1] * inv - mean * mean;
    float rstd = rsqrtf(var + EPS_);
    float v = x[(((size_t)(b * 64 + c)) * 128 + f) * Tt + t];
    xu[((size_t)(n * 64 + c) << 8) + t] = (v - mean) * rstd * gamma[c] + beta[c];
}

// ---------------- pack all weights to bf16 (transposed to [out][k] layouts) ----------------
__global__ void k_packw(const float* __restrict__ W0, const float* __restrict__ Wr,
                        const float* __restrict__ wct,
                        u16* __restrict__ W0t, u16* __restrict__ Wrt, u16* __restrict__ Wcto) {
    int idx = blockIdx.x * blockDim.x + threadIdx.x;
    if (idx < 131072) {
        int j = idx >> 9, p = idx & 511;
        W0t[idx] = f2bf(W0[(size_t)(j >> 7) * 65536 + p * 128 + (j & 127)]);
    } else if (idx < 180224) {
        int r = idx - 131072;
        int i = r & 63, j = (r >> 6) & 255, lidx = r >> 14;
        Wrt[r] = f2bf(Wr[(size_t)(lidx * 2 + (j >> 7)) * 8192 + i * 128 + (j & 127)]);
    } else if (idx < 212992) {
        int r = idx - 180224;
        int o = r >> 9; int k = r & 511; int kk = k >> 6, ci = k & 63;
        Wcto[r] = f2bf(wct[(size_t)ci * 512 + o * 8 + kk]);
    }
}

// ---------------- im2col: Abig[t*256+n][c*8+kk] = bf16(xu[n][c][t+kk]) ----------------
__global__ __launch_bounds__(256) void k_im2col(const float* __restrict__ xu, u16* __restrict__ A) {
    __shared__ u16 lx[8][64][40];
    int t0 = blockIdx.x * 32;
    int n0 = blockIdx.y * 8;
    int tid = threadIdx.x;
    #pragma unroll
    for (int it = 0; it < 20; ++it) {
        int task = tid + it * 256;
        int v = task % 10;
        int c = (task / 10) & 63;
        int nn = task / 640;
        float4 f4 = *(const float4*)&xu[((size_t)((n0 + nn) * 64 + c) << 8) + t0 + v * 4];
        lx[nn][c][v * 4 + 0] = f2bf(f4.x);
        lx[nn][c][v * 4 + 1] = f2bf(f4.y);
        lx[nn][c][v * 4 + 2] = f2bf(f4.z);
        lx[nn][c][v * 4 + 3] = f2bf(f4.w);
    }
    __syncthreads();
    for (int it = 0; it < 64; ++it) {
        int task = it * 256 + tid;
        int c = task & 63, nn = (task >> 6) & 7, tt = task >> 9;
        int t = t0 + tt;
        if (t >= TnN) break;
        u16 tmp[8];
        #pragma unroll
        for (int j = 0; j < 8; ++j) tmp[j] = lx[nn][c][tt + j];
        uint4 o;
        o.x = (unsigned)tmp[0] | ((unsigned)tmp[1] << 16);
        o.y = (unsigned)tmp[2] | ((unsigned)tmp[3] << 16);
        o.z = (unsigned)tmp[4] | ((unsigned)tmp[5] << 16);
        o.w = (unsigned)tmp[6] | ((unsigned)tmp[7] << 16);
        *(uint4*)&A[((size_t)t * 256 + n0 + nn) * 512 + c * 8] = o;
    }
}

// ---------------- MFMA GEMM layer 0: 128x128 tile, epilogue -> U2[(n*2+d)*243+t][128] ----------------
__global__ __launch_bounds__(256) void k_gemm0m(const u16* __restrict__ A,
                                                const u16* __restrict__ B,
                                                u16* __restrict__ U2) {
    __shared__ u16 sh[16384];
    u16* As = sh;
    u16* Bs = sh + 5120;
    const int tid = threadIdx.x;
    const size_t m0 = (size_t)blockIdx.x * 128;
    const int t = blockIdx.x >> 1;             // tile covers fixed t
    const int n0 = (blockIdx.x & 1) * 128;
    const int j0 = blockIdx.y * 128;
    const int d = blockIdx.y;                  // j0>>7
    const int lane = tid & 63, w = tid >> 6;
    const int wr = w >> 1, wc = w & 1;
    const int ml = lane & 15, q = lane >> 4;
    f32x4 acc[4][4] = {};
    for (int kc = 0; kc < 16; ++kc) {
        int c0 = kc * 32;
        #pragma unroll
        for (int i = 0; i < 2; ++i) {
            int task = tid + i * 256;
            int row = task >> 2, grp = task & 3;
            *(uint4*)&As[row * 40 + grp * 8] = *(const uint4*)&A[(m0 + row) * 512 + c0 + grp * 8];
            *(uint4*)&Bs[row * 40 + grp * 8] = *(const uint4*)&B[(size_t)(j0 + row) * 512 + c0 + grp * 8];
        }
        __syncthreads();
        bf16x8 af[4], bfv[4];
        #pragma unroll
        for (int mt = 0; mt < 4; ++mt) af[mt] = *(const bf16x8*)&As[(wr * 64 + mt * 16 + ml) * 40 + q * 8];
        #pragma unroll
        for (int nt = 0; nt < 4; ++nt) bfv[nt] = *(const bf16x8*)&Bs[(wc * 64 + nt * 16 + ml) * 40 + q * 8];
        #pragma unroll
        for (int mt = 0; mt < 4; ++mt)
            #pragma unroll
            for (int nt = 0; nt < 4; ++nt)
                acc[mt][nt] = __builtin_amdgcn_mfma_f32_16x16x32_bf16(af[mt], bfv[nt], acc[mt][nt], 0, 0, 0);
        __syncthreads();
    }
    u16* Cw = sh + w * 4096;
    #pragma unroll
    for (int mt = 0; mt < 4; ++mt)
        #pragma unroll
        for (int nt = 0; nt < 4; ++nt)
            #pragma unroll
            for (int r = 0; r < 4; ++r)
                Cw[(mt * 16 + q * 4 + r) * 64 + nt * 16 + ml] = f2bf(acc[mt][nt][r]);
    __syncthreads();
    #pragma unroll
    for (int it = 0; it < 8; ++it) {
        int task = it * 64 + lane;
        int grp = task & 7, row = task >> 3;
        int n = n0 + wr * 64 + row;
        // U2[(n*2+d)*243 + t][jj], jj = wc*64 + grp*8
        *(uint4*)&U2[((size_t)(n * 2 + d) * 243 + t) * 128 + wc * 64 + grp * 8] =
            *(const uint4*)&Cw[row * 64 + grp * 8];
    }
}

// ---------------- SRU scan layer 0: streaming U2, one block per (n,d) ----------------
__global__ __launch_bounds__(64) void k_scan0(const u16* __restrict__ U2,
                                              const float* __restrict__ v,
                                              const float* __restrict__ bbias,
                                              u16* __restrict__ hout) {
    __shared__ u16 lds[2][8 * 136];
    const int lane = threadIdx.x;
    const int n = blockIdx.x >> 1, d = blockIdx.x & 1;
    const int h = lane & 31;
    const float* vv = v + (size_t)d * 64;       // layer 0
    const float* bv = bbias + (size_t)d * 64;
    const float vf = vv[h], vr = vv[32 + h], bf_ = bv[h], br_ = bv[32 + h];
    const int t0 = d ? (TnN - 1) : 0;
    const int dt = d ? -1 : 1;
    const u16* Ub = U2 + (size_t)(n * 2 + d) * 243 * 128;
    const int l_row[2] = { lane >> 4, (64 + lane) >> 4 };
    const int l_col = lane & 15;
    uint4 pre[2];

    #pragma unroll
    for (int it = 0; it < 2; ++it) {
        int t = t0 + dt * l_row[it];
        pre[it] = *(const uint4*)&Ub[(size_t)t * 128 + l_col * 8];
    }
    #pragma unroll
    for (int it = 0; it < 2; ++it)
        *(uint4*)&lds[0][l_row[it] * 136 + l_col * 8] = pre[it];
    __syncthreads();

    float c = 0.f;
    for (int g0 = 0; g0 < TnN; g0 += 8) {
        const int buf = (g0 >> 3) & 1;
        const bool more = (g0 + 8) < TnN;
        if (more) {
            #pragma unroll
            for (int it = 0; it < 2; ++it) {
                int g = g0 + 8 + l_row[it];
                int gc = g < TnN ? g : (TnN - 1);
                int t = t0 + dt * gc;
                pre[it] = *(const uint4*)&Ub[(size_t)t * 128 + l_col * 8];
            }
        }
        float gz[8], gf[8], gr_[8], gx[8];
        #pragma unroll
        for (int u = 0; u < 8; ++u) {
            const u16* row = &lds[buf][u * 136];
            gz[u] = bf2f(row[h]);
            gf[u] = bf2f(row[32 + h]);
            gr_[u] = bf2f(row[64 + h]);
            gx[u] = bf2f(row[96 + h]);
        }
        #pragma unroll
        for (int u = 0; u < 8; ++u) {
            int g = g0 + u;
            if (g < TnN && lane < 32) {
                float fg = 1.f / (1.f + __expf(-(gf[u] + vf * c + bf_)));
                float rg = 1.f / (1.f + __expf(-(gr_[u] + vr * c + br_)));
                c = fg * c + (1.f - fg) * gz[u];
                float hv = rg * c + (1.f - rg) * gx[u];
                int t = t0 + dt * g;
                hout[((size_t)n * 243 + t) * 64 + d * 32 + h] = f2bf(hv);
            }
        }
        if (more) {
            #pragma unroll
            for (int it = 0; it < 2; ++it)
                *(uint4*)&lds[buf ^ 1][l_row[it] * 136 + l_col * 8] = pre[it];
        }
        __syncthreads();
    }
}

// ---------------- fused layer (1..3): GEMM (K=64) + scan, one block per (n, d) ----------------
// h layout: h[n][t][64] (n-major, contiguous 31 KB per n)
__global__ __launch_bounds__(256) void k_layer(const u16* __restrict__ hin,
                                               const u16* __restrict__ Wrt_l, // [256 j][64 i]
                                               const float* __restrict__ v,
                                               const float* __restrict__ bbias,
                                               u16* __restrict__ hout, int layer) {
    __shared__ u16 sh[32768];   // 64 KiB
    u16* Ah = sh;               // 256 rows x 72
    u16* Bs = sh + 256 * 72;    // 128 rows x 72
    const int tid = threadIdx.x;
    const int n = blockIdx.x, d = blockIdx.y;
    #pragma unroll
    for (int it = 0; it < 8; ++it) {
        int task = it * 256 + tid;
        int row = task >> 3, grp = task & 7;
        uint4 val = make_uint4(0, 0, 0, 0);
        if (row < TnN)
            val = *(const uint4*)&hin[((size_t)n * 243 + row) * 64 + grp * 8];
        *(uint4*)&Ah[row * 72 + grp * 8] = val;
    }
    #pragma unroll
    for (int it = 0; it < 4; ++it) {
        int task = it * 256 + tid;
        int j = task >> 3, grp = task & 7;
        *(uint4*)&Bs[j * 72 + grp * 8] = *(const uint4*)&Wrt_l[((size_t)(d * 128 + j)) * 64 + grp * 8];
    }
    __syncthreads();
    const int lane = tid & 63, w = tid >> 6;
    const int ml = lane & 15, q = lane >> 4;
    f32x4 acc[4][8] = {};
    #pragma unroll
    for (int c2 = 0; c2 < 2; ++c2) {
        int c0 = c2 * 32;
        bf16x8 af[4];
        #pragma unroll
        for (int mt = 0; mt < 4; ++mt)
            af[mt] = *(const bf16x8*)&Ah[(w * 64 + mt * 16 + ml) * 72 + c0 + q * 8];
        #pragma unroll
        for (int nt = 0; nt < 8; ++nt) {
            bf16x8 bfr = *(const bf16x8*)&Bs[(nt * 16 + ml) * 72 + c0 + q * 8];
            #pragma unroll
            for (int mt = 0; mt < 4; ++mt)
                acc[mt][nt] = __builtin_amdgcn_mfma_f32_16x16x32_bf16(af[mt], bfr, acc[mt][nt], 0, 0, 0);
        }
    }
    __syncthreads();
    u16* Ul = sh;               // 243 rows x 132
    #pragma unroll
    for (int mt = 0; mt < 4; ++mt)
        #pragma unroll
        for (int r = 0; r < 4; ++r) {
            int t = w * 64 + mt * 16 + q * 4 + r;
            if (t < TnN) {
                #pragma unroll
                for (int nt = 0; nt < 8; ++nt)
                    Ul[t * 132 + nt * 16 + ml] = f2bf(acc[mt][nt][r]);
            }
        }
    __syncthreads();
    if (tid >= 32) return;
    const int h = tid;
    const float* vv = v + (size_t)(layer * 2 + d) * 64;
    const float* bv = bbias + (size_t)(layer * 2 + d) * 64;
    const float vf = vv[h], vr = vv[32 + h], bf_ = bv[h], br_ = bv[32 + h];
    const int t0 = d ? (TnN - 1) : 0;
    const int dt = d ? -1 : 1;
    float c = 0.f;
    for (int g0 = 0; g0 < TnN; g0 += 8) {
        float gz[8], gf[8], gr_[8], gx[8];
        #pragma unroll
        for (int u = 0; u < 8; ++u) {
            int g = g0 + u; int gg = g < TnN ? g : (TnN - 1);
            int t = t0 + dt * gg;
            const u16* row = &Ul[t * 132];
            gz[u] = bf2f(row[h]); gf[u] = bf2f(row[32 + h]);
            gr_[u] = bf2f(row[64 + h]); gx[u] = bf2f(row[96 + h]);
        }
        #pragma unroll
        for (int u = 0; u < 8; ++u) {
            int g = g0 + u;
            if (g < TnN) {
                float fg = 1.f / (1.f + __expf(-(gf[u] + vf * c + bf_)));
                float rg = 1.f / (1.f + __expf(-(gr_[u] + vr * c + br_)));
                c = fg * c + (1.f - fg) * gz[u];
                float hv = rg * c + (1.f - rg) * gx[u];
                int t = t0 + dt * g;
                hout[((size_t)n * 243 + t) * 64 + d * 32 + h] = f2bf(hv);
            }
        }
    }
}

// ---------------- final conv per-n block: MFMA + bias + residual ----------------
__global__ __launch_bounds__(256) void k_convm(const u16* __restrict__ hL,   // [n][t][64]
                                               const u16* __restrict__ Wc,   // [64 o][512 k]
                                               const float* __restrict__ bct,
                                               const float* __restrict__ x,
                                               float* __restrict__ out) {
    __shared__ u16 As[264 * 72];   // rows: tau+7 for tau in [-7..256]; guards zeroed
    __shared__ u16 Bs[64 * 40];
    const int tid = threadIdx.x;
    const int n = blockIdx.x;
    const int b = n >> 7, f = n & 127;
    #pragma unroll
    for (int it = 0; it < 8; ++it) {
        int task = it * 256 + tid;
        int row = task >> 3, grp = task & 7;
        if (row < TnN)
            *(uint4*)&As[(row + 7) * 72 + grp * 8] = *(const uint4*)&hL[((size_t)n * 243 + row) * 64 + grp * 8];
    }
    if (tid < 168) {               // zero guards: rows 0..6 and 250..263
        int r = tid >> 3, grp = tid & 7;
        int row = r < 7 ? r : (TnN + r);
        *(uint4*)&As[row * 72 + grp * 8] = make_uint4(0, 0, 0, 0);
    }
    const int lane = tid & 63, w = tid >> 6;
    const int ml = lane & 15, q = lane >> 4;
    f32x4 acc[4][4] = {};
    for (int kc = 0; kc < 16; ++kc) {
        int kk = kc >> 1, ci0 = (kc & 1) * 32;
        {
            int o = tid >> 2, grp = tid & 3;   // all 256 threads, full 32 columns
            *(uint4*)&Bs[o * 40 + grp * 8] = *(const uint4*)&Wc[(size_t)o * 512 + kc * 32 + grp * 8];
        }
        __syncthreads();
        bf16x8 af[4], bfv[4];
        #pragma unroll
        for (int mt = 0; mt < 4; ++mt)
            af[mt] = *(const bf16x8*)&As[(w * 64 + mt * 16 + ml - kk + 7) * 72 + ci0 + q * 8];
        #pragma unroll
        for (int nt = 0; nt < 4; ++nt)
            bfv[nt] = *(const bf16x8*)&Bs[(nt * 16 + ml) * 40 + q * 8];
        #pragma unroll
        for (int mt = 0; mt < 4; ++mt)
            #pragma unroll
            for (int nt = 0; nt < 4; ++nt)
                acc[mt][nt] = __builtin_amdgcn_mfma_f32_16x16x32_bf16(af[mt], bfv[nt], acc[mt][nt], 0, 0, 0);
        __syncthreads();
    }
    float bc[4];
    #pragma unroll
    for (int nt = 0; nt < 4; ++nt) bc[nt] = bct[nt * 16 + ml];
    #pragma unroll
    for (int mt = 0; mt < 4; ++mt)
        #pragma unroll
        for (int r = 0; r < 4; ++r) {
            int t = w * 64 + mt * 16 + q * 4 + r;
            if (t < Tt) {
                #pragma unroll
                for (int nt = 0; nt < 4; ++nt) {
                    int o = nt * 16 + ml;
                    size_t idx = ((size_t)(b * 64 + o) * 128 + f) * Tt + t;
                    out[idx] = acc[mt][nt][r] + bc[nt] + x[idx];
                }
            }
        }
}

extern "C" void kernel_launch(void* const* d_in, const int* in_sizes, int n_in,
                              void* d_out, int out_size, void* d_ws, size_t ws_size,
                              hipStream_t stream) {
    (void)in_sizes; (void)n_in; (void)out_size; (void)ws_size;
    const float* x     = (const float*)d_in[0];
    const float* gamma = (const float*)d_in[1];
    const float* beta  = (const float*)d_in[2];
    const float* W0    = (const float*)d_in[3];
    const float* Wr    = (const float*)d_in[4];
    const float* v     = (const float*)d_in[5];
    const float* bb    = (const float*)d_in[6];
    const float* wct   = (const float*)d_in[7];
    const float* bct   = (const float*)d_in[8];
    float* out = (float*)d_out;

    char* base = (char*)d_ws;
    float* stats = (float*)base;
    u16* W0t  = (u16*)(base + 256);                      // 262144 B
    u16* Wrt  = (u16*)(base + 256 + 262144);             // 98304 B
    u16* Wcto = (u16*)(base + 256 + 262144 + 98304);     // 65536 B
    char* base2 = base + 426240;
    float* xu = (float*)base2;                           // 16.8 MB (dead after im2col)
    u16* U2   = (u16*)base2;                             // alias: 31.85 MB (live gemm0m->scan0)
    char* base3 = base2 + 31850496;
    u16* Abig = (u16*)base3;                             // 63.7 MB (dead after gemm0m)
    u16* h0   = (u16*)base3;                             // alias Abig
    u16* h1   = (u16*)(base3 + 8 * 1024 * 1024);         // alias Abig+8MB

    hipMemsetAsync(stats, 0, 32, stream);
    k_stats<<<dim3(128, 2), 256, 0, stream>>>(x, stats);
    k_norm<<<(Nn * 64 * Tt + 255) / 256, 256, 0, stream>>>(x, stats, gamma, beta, xu);
    k_packw<<<(212992 + 255) / 256, 256, 0, stream>>>(W0, Wr, wct, W0t, Wrt, Wcto);
    k_im2col<<<dim3(8, 32), 256, 0, stream>>>(xu, Abig);

    k_gemm0m<<<dim3(486, 2), 256, 0, stream>>>(Abig, W0t, U2);
    k_scan0<<<dim3(512), 64, 0, stream>>>(U2, v, bb, h0);

    k_layer<<<dim3(256, 2), 256, 0, stream>>>(h0, Wrt,         v, bb, h1, 1);
    k_layer<<<dim3(256, 2), 256, 0, stream>>>(h1, Wrt + 16384, v, bb, h0, 2);
    k_layer<<<dim3(256, 2), 256, 0, stream>>>(h0, Wrt + 32768, v, bb, h1, 3);

    k_convm<<<dim3(256), 256, 0, stream>>>(h1, Wcto, bct, x, out);
}